// Round 3
// baseline (276.788 us; speedup 1.0000x reference)
//
#include <hip/hip_runtime.h>
#include <hip/hip_bf16.h>
#include <cstdint>

#define B_ 16
#define N_ 2048
#define D_ 64

typedef __bf16 bf16x8_t __attribute__((ext_vector_type(8)));
typedef __bf16 bf16x4_t __attribute__((ext_vector_type(4)));
typedef float f32x4_t __attribute__((ext_vector_type(4)));
typedef int   int4_t  __attribute__((ext_vector_type(4)));

#define ESTR 2056                  // E row stride in bf16 elems (4112 B: %16==0, avoids pow2 banks)
#define EBYTES (16 * ESTR * 2)     // 65792
#define VBASE  EBYTES              // 8 waves x 4096 B V staging ([t:4][n:32][d:16] bf16 subtiles)
#define VSZ    (8 * 4096)          // 32768 ; reused as O-reduction buffer in epilogue
#define LBASE  (VBASE + VSZ)       // 98560 : 8 waves x 16 row-sums (fp32)
#define RBASE  (LBASE + 8 * 16 * 4)// 99072 : 16 x rinv
#define LDSZ   (RBASE + 64)        // 99136

__device__ __forceinline__ void split8(const float* p, bf16x8_t& h, bf16x8_t& lo) {
    f32x4_t a  = *(const f32x4_t*)p;
    f32x4_t bq = *(const f32x4_t*)(p + 4);
    #pragma unroll
    for (int j = 0; j < 4; ++j) {
        __bf16 h0 = (__bf16)a[j];
        h[j] = h0;     lo[j]     = (__bf16)(a[j]  - (float)h0);
        __bf16 h1 = (__bf16)bq[j];
        h[4 + j] = h1; lo[4 + j] = (__bf16)(bq[j] - (float)h1);
    }
}

__global__ __launch_bounds__(512, 1)
void attn_fused(const float* __restrict__ qg,
                const float* __restrict__ kg,
                const float* __restrict__ vg,
                const int*   __restrict__ mg,
                float* __restrict__ out0,
                float* __restrict__ out1)
{
    __shared__ __align__(16) char lds[LDSZ];
    __bf16* Ebase = (__bf16*)lds;

    const int tid = threadIdx.x;
    const int w = tid >> 6, l = tid & 63, g = l >> 4, c = l & 15;
    const int b  = blockIdx.x >> 7;
    const int m0 = (blockIdx.x & 127) << 4;

    // Q fragments (split hi/lo bf16): A-frag row = c (q-row m0+c), k-slot (g,j) <-> d = g*8+j (+32 frag1)
    bf16x8_t qh0, ql0, qh1, ql1;
    {
        const float* qrow = qg + ((size_t)(b * N_ + m0 + c)) * D_ + g * 8;
        split8(qrow,      qh0, ql0);
        split8(qrow + 32, qh1, ql1);
    }

    const int* mbase = mg + (size_t)b * N_ * N_ + (size_t)(m0 + g * 4) * N_ + c;

    // V staging: lane loads rows nc+u*8+(l>>3), cols (l&7)*8..+8 (fp32) -> bf16 -> subtiled LDS
    char* Vw = lds + VBASE + w * 4096;
    const int vst_off = (((l & 7) >> 1) << 10) | ((l >> 3) << 5) | ((l & 1) << 4);
    const float* vsrc0 = vg + ((size_t)(b * N_) + (l >> 3)) * D_ + (l & 7) * 8;

    const int nc0 = w * 256;
    float lsum[4] = {0.f, 0.f, 0.f, 0.f};
    f32x4_t of[4] = {};   // O_unnorm[g*4+r][t*16+c]

    #pragma unroll 1
    for (int nc = nc0; nc < nc0 + 256; nc += 32) {
        // ---- stage V[nc..nc+32) ----
        #pragma unroll
        for (int u = 0; u < 4; ++u) {
            const float* p = vsrc0 + (size_t)(nc + u * 8) * D_;
            f32x4_t a  = *(const f32x4_t*)p;
            f32x4_t bq = *(const f32x4_t*)(p + 4);
            bf16x8_t v8;
            #pragma unroll
            for (int j = 0; j < 4; ++j) { v8[j] = (__bf16)a[j]; v8[4 + j] = (__bf16)bq[j]; }
            *(int4_t*)(Vw + vst_off + u * 256) = __builtin_bit_cast(int4_t, v8);
        }

        // ---- scores (split-bf16, fp32-accurate) -> masked exp -> E tile ----
        #pragma unroll
        for (int s = 0; s < 2; ++s) {
            const int nn = nc + s * 16;
            const float* krow = kg + ((size_t)(b * N_ + nn + c)) * D_ + g * 8;
            bf16x8_t kh0, kl0, kh1, kl1;
            split8(krow,      kh0, kl0);
            split8(krow + 32, kh1, kl1);
            f32x4_t acc = {0.f, 0.f, 0.f, 0.f};
            acc = __builtin_amdgcn_mfma_f32_16x16x32_bf16(qh0, kh0, acc, 0, 0, 0);
            acc = __builtin_amdgcn_mfma_f32_16x16x32_bf16(qh1, kh1, acc, 0, 0, 0);
            acc = __builtin_amdgcn_mfma_f32_16x16x32_bf16(ql0, kh0, acc, 0, 0, 0);
            acc = __builtin_amdgcn_mfma_f32_16x16x32_bf16(ql1, kh1, acc, 0, 0, 0);
            acc = __builtin_amdgcn_mfma_f32_16x16x32_bf16(qh0, kl0, acc, 0, 0, 0);
            acc = __builtin_amdgcn_mfma_f32_16x16x32_bf16(qh1, kl1, acc, 0, 0, 0);
            const int* mp = mbase + nn;
            #pragma unroll
            for (int r = 0; r < 4; ++r) {
                int mb = mp[(size_t)r * N_];               // nonzero -> masked -> 0
                float e = mb ? 0.f : __expf(acc[r]);
                lsum[r] += e;
                Ebase[(g * 4 + r) * ESTR + nn + c] = (__bf16)e;
            }
        }

        // ---- PV: A-frag from E (k-slot j <-> n = nc+g*4+j, 4+j <-> nc+16+g*4+j) ----
        bf16x4_t plo = *(const bf16x4_t*)(Ebase + (size_t)c * ESTR + nc + g * 4);
        bf16x4_t phi = *(const bf16x4_t*)(Ebase + (size_t)c * ESTR + nc + 16 + g * 4);
        bf16x8_t pa = __builtin_shufflevector(plo, phi, 0, 1, 2, 3, 4, 5, 6, 7);

        // ---- B-frag: plain scalar LDS reads, exactly the same k-map: V[nc+g*4+j][t*16+c] ----
        #pragma unroll
        for (int t = 0; t < 4; ++t) {
            const __bf16* vs = (const __bf16*)(Vw + t * 1024) + c;   // subtile rows: 16 elems apart
            bf16x8_t vbf;
            #pragma unroll
            for (int j = 0; j < 4; ++j) {
                vbf[j]     = vs[(g * 4 + j) * 16];
                vbf[4 + j] = vs[(16 + g * 4 + j) * 16];
            }
            of[t] = __builtin_amdgcn_mfma_f32_16x16x32_bf16(pa, vbf, of[t], 0, 0, 0);
        }
    }

    // =============== epilogue ===============
    __syncthreads();

    // row sums: reduce over c lanes, stash per wave
    float* Lbuf = (float*)(lds + LBASE);
    #pragma unroll
    for (int r = 0; r < 4; ++r) {
        float s = lsum[r];
        s += __shfl_xor(s, 1); s += __shfl_xor(s, 2);
        s += __shfl_xor(s, 4); s += __shfl_xor(s, 8);
        lsum[r] = s;
    }
    if (c == 0) {
        #pragma unroll
        for (int r = 0; r < 4; ++r) Lbuf[w * 16 + g * 4 + r] = lsum[r];
    }
    __syncthreads();

    float* Rinv = (float*)(lds + RBASE);
    if (tid < 16) {
        float s = 0.f;
        #pragma unroll
        for (int ww = 0; ww < 8; ++ww) s += Lbuf[ww * 16 + tid];
        Rinv[tid] = 1.0f / s;
    }
    __syncthreads();

    // O partials into (dead) V region: [w][row16][d64] fp32
    float* Ored = (float*)(lds + VBASE);
    #pragma unroll
    for (int t = 0; t < 4; ++t) {
        #pragma unroll
        for (int r = 0; r < 4; ++r)
            Ored[w * 1024 + (g * 4 + r) * 64 + t * 16 + c] = of[t][r];
    }
    __syncthreads();

    // out0: [16 rows][64 d] fp32, sum 8 waves, scale by rinv
    if (tid < 256) {
        const int row = tid >> 4;
        const int dc  = (tid & 15) * 4;
        const float ri = Rinv[row];
        f32x4_t o = {0.f, 0.f, 0.f, 0.f};
        #pragma unroll
        for (int ww = 0; ww < 8; ++ww)
            o += *(const f32x4_t*)(Ored + ww * 1024 + row * 64 + dc);
        o.x *= ri; o.y *= ri; o.z *= ri; o.w *= ri;
        *(f32x4_t*)(out0 + ((size_t)(b * N_ + m0 + row)) * D_ + dc) = o;
    }

    // out1: P = E * rinv, fp32, coalesced (32 threads/row x 8-col chunks)
    {
        const int row = tid >> 5;
        const int cb  = (tid & 31) * 8;
        const float ri = Rinv[row];
        const __bf16* Er = Ebase + (size_t)row * ESTR;
        float* o1 = out1 + (size_t)b * N_ * N_ + (size_t)(m0 + row) * N_;
        #pragma unroll 1
        for (int it = 0; it < 8; ++it) {
            const int col = cb + it * 256;
            bf16x8_t ev = *(const bf16x8_t*)(Er + col);
            f32x4_t w0, w1;
            #pragma unroll
            for (int j = 0; j < 4; ++j) {
                w0[j] = (float)ev[j] * ri;
                w1[j] = (float)ev[4 + j] * ri;
            }
            *(f32x4_t*)(o1 + col) = w0;
            *(f32x4_t*)(o1 + col + 4) = w1;
        }
    }
}

extern "C" void kernel_launch(void* const* d_in, const int* in_sizes, int n_in,
                              void* d_out, int out_size, void* d_ws, size_t ws_size,
                              hipStream_t stream) {
    (void)in_sizes; (void)n_in; (void)out_size; (void)d_ws; (void)ws_size;
    const float* q = (const float*)d_in[0];
    const float* k = (const float*)d_in[1];
    const float* v = (const float*)d_in[2];
    const int* mask = (const int*)d_in[3];
    float* out0 = (float*)d_out;                          // [B,N,D]
    float* out1 = out0 + (size_t)B_ * N_ * D_;            // [B,N,N]
    attn_fused<<<dim3(B_ * (N_ / 16)), dim3(512), 0, stream>>>(q, k, v, mask, out0, out1);
}

// Round 4
// 267.891 us; speedup vs baseline: 1.0332x; 1.0332x over previous
//
#include <hip/hip_runtime.h>
#include <hip/hip_bf16.h>
#include <cstdint>

#define B_ 16
#define N_ 2048
#define D_ 64

typedef __bf16 bf16x8_t __attribute__((ext_vector_type(8)));
typedef __bf16 bf16x4_t __attribute__((ext_vector_type(4)));
typedef float f32x4_t __attribute__((ext_vector_type(4)));
typedef int   int4_t  __attribute__((ext_vector_type(4)));

// LDS map (bytes):
//  [0, 67584)        8 waves x WVREG(8448): V staging, 2 bufs x (4 subtiles x TSUB 1056B).
//                    buf0's first 4096B reused as per-wave O-reduction region in epilogue.
//  [67584, 77824)    8 waves x 1280: E transpose tile [16 m][40 n] bf16 (row stride 80B)
//  [77824, 78336)    Lbuf: 8 waves x 16 row-sums (f32)
//  [78336, 78400)    Rinv: 16 f32
#define TSUB  1056
#define VBUF  (4 * TSUB)      // 4224
#define WVREG (2 * VBUF)      // 8448
#define EBASE (8 * WVREG)     // 67584
#define EW    1280
#define LBASE (EBASE + 8 * EW)    // 77824
#define RBASE (LBASE + 8 * 16 * 4)// 78336
#define LDSZ  (RBASE + 64)        // 78400  (<80KB -> 2 blocks/CU)

__device__ __forceinline__ void split8(const float* p, bf16x8_t& h, bf16x8_t& lo) {
    f32x4_t a  = *(const f32x4_t*)p;
    f32x4_t bq = *(const f32x4_t*)(p + 4);
    #pragma unroll
    for (int j = 0; j < 4; ++j) {
        __bf16 h0 = (__bf16)a[j];
        h[j] = h0;     lo[j]     = (__bf16)(a[j]  - (float)h0);
        __bf16 h1 = (__bf16)bq[j];
        h[4 + j] = h1; lo[4 + j] = (__bf16)(bq[j] - (float)h1);
    }
}

__global__ __launch_bounds__(512, 4)
void attn_fused(const float* __restrict__ qg,
                const float* __restrict__ kg,
                const float* __restrict__ vg,
                const int*   __restrict__ mg,
                float* __restrict__ out0,
                float* __restrict__ out1)
{
    __shared__ __align__(16) char lds[LDSZ];

    const int tid = threadIdx.x;
    const int w = tid >> 6, l = tid & 63, g = l >> 4, c = l & 15;

    // XCD-chunked bijective swizzle (2048 blocks % 8 == 0)
    const int bid = ((int)blockIdx.x & 7) * 256 + ((int)blockIdx.x >> 3);
    const int b  = bid >> 7;
    const int m0 = (bid & 127) << 4;

    // Q as MFMA B-operand: col=c -> q-row m0+c; k-slot (g,j) <-> d = g*8+j (+32 frag1)
    bf16x8_t qh0, ql0, qh1, ql1;
    {
        const float* qrow = qg + ((size_t)(b * N_ + m0 + c)) * D_ + g * 8;
        split8(qrow,      qh0, ql0);
        split8(qrow + 32, qh1, ql1);
    }

    const int* mrow = mg + (size_t)(b * N_ + m0 + c) * N_;   // mask row of q-row m0+c
    const float* vsrc0 = vg + ((size_t)(b * N_) + (l >> 3)) * D_ + (l & 7) * 8;

    char* VW = lds + w * WVREG;
    const int tsub  = ((l & 7) >> 1) * TSUB;   // which d-subtile this lane stages into
    const int wrow0 = l >> 3;                  // staging row (0..7), +8 per u
    const int wcolb = (l & 1) * 16;            // 16B half of a 32B row
    const int hbit  = (l >> 5) & 1;
    const int vrd_base = g * 128 + c * 2;      // read: byte = g*128 + 32*(j^g) + 2c (XOR-swz closed form)

    const int nc0 = w * 256;
    float lsum = 0.f;
    f32x4_t of[4] = {};     // O_unnorm: lane (g,c) holds O[m=4g+r][d=16t+c]
    bf16x8_t pa[8];         // per-chunk P rows (A-frag layout), statically indexed

    #pragma unroll
    for (int ic = 0; ic < 8; ++ic) {
        const int nc = nc0 + ic * 32;
        char* vbuf = VW + (ic & 1) * VBUF;

        // ---- stage V[nc..nc+32) -> bf16, swizzled subtiles ----
        #pragma unroll
        for (int u = 0; u < 4; ++u) {
            const float* p = vsrc0 + (size_t)(nc + u * 8) * D_;
            f32x4_t a  = *(const f32x4_t*)p;
            f32x4_t b2 = *(const f32x4_t*)(p + 4);
            bf16x8_t v8;
            #pragma unroll
            for (int j = 0; j < 4; ++j) { v8[j] = (__bf16)a[j]; v8[4 + j] = (__bf16)b2[j]; }
            const int off = (((wrow0 + 8 * u) * 32 + wcolb) ^ (((hbit + 2 * u) & 3) << 5));
            *(int4_t*)(vbuf + tsub + off) = __builtin_bit_cast(int4_t, v8);
        }

        // ---- S^T = K·Q^T (swapped): lane (g,c) gets S[n=nn+4g+r][m=m0+c] ----
        bf16x4_t eh[2];
        #pragma unroll
        for (int s = 0; s < 2; ++s) {
            const int nn = nc + s * 16;
            const float* krow = kg + ((size_t)(b * N_ + nn + c)) * D_ + g * 8;
            bf16x8_t kh0, kl0, kh1, kl1;
            split8(krow,      kh0, kl0);
            split8(krow + 32, kh1, kl1);
            f32x4_t acc = {0.f, 0.f, 0.f, 0.f};
            acc = __builtin_amdgcn_mfma_f32_16x16x32_bf16(kh0, qh0, acc, 0, 0, 0);
            acc = __builtin_amdgcn_mfma_f32_16x16x32_bf16(kh1, qh1, acc, 0, 0, 0);
            acc = __builtin_amdgcn_mfma_f32_16x16x32_bf16(kl0, qh0, acc, 0, 0, 0);
            acc = __builtin_amdgcn_mfma_f32_16x16x32_bf16(kl1, qh1, acc, 0, 0, 0);
            acc = __builtin_amdgcn_mfma_f32_16x16x32_bf16(kh0, ql0, acc, 0, 0, 0);
            acc = __builtin_amdgcn_mfma_f32_16x16x32_bf16(kh1, ql1, acc, 0, 0, 0);
            const int4_t mv = *(const int4_t*)(mrow + nn + g * 4);   // mask[m][nn+4g+r], r=0..3
            #pragma unroll
            for (int r = 0; r < 4; ++r) {
                float ev = mv[r] ? 0.f : __expf(acc[r]);
                lsum += ev;
                eh[s][r] = (__bf16)ev;
            }
        }
        pa[ic] = __builtin_shufflevector(eh[0], eh[1], 0, 1, 2, 3, 4, 5, 6, 7);

        // ---- PV: A=pa (in regs!), B=V from swizzled LDS (conflict-free scalar reads) ----
        #pragma unroll
        for (int t = 0; t < 4; ++t) {
            const char* vs = vbuf + t * TSUB;
            bf16x8_t vbf;
            #pragma unroll
            for (int j = 0; j < 4; ++j) {
                const int off = vrd_base + ((j ^ g) & 3) * 32;
                vbf[j]     = *(const __bf16*)(vs + off);
                vbf[4 + j] = *(const __bf16*)(vs + off + 512);
            }
            of[t] = __builtin_amdgcn_mfma_f32_16x16x32_bf16(pa[ic], vbf, of[t], 0, 0, 0);
        }
    }

    // =============== epilogue ===============
    // O partials into own wave's (dead) V buf0 region: [16 m][64 d] f32
    {
        float* Ow = (float*)VW;
        #pragma unroll
        for (int t = 0; t < 4; ++t)
            #pragma unroll
            for (int r = 0; r < 4; ++r)
                Ow[(g * 4 + r) * 64 + t * 16 + c] = of[t][r];
    }

    // row sums: lane (g,c) has partial of row c; sum over g via shfl, stash per wave
    lsum += __shfl_xor(lsum, 16);
    lsum += __shfl_xor(lsum, 32);
    float* Lbuf = (float*)(lds + LBASE);
    if (l < 16) Lbuf[w * 16 + l] = lsum;
    __syncthreads();

    float* Rinv = (float*)(lds + RBASE);
    if (tid < 16) {
        float s = 0.f;
        #pragma unroll
        for (int ww = 0; ww < 8; ++ww) s += Lbuf[ww * 16 + tid];
        Rinv[tid] = 1.0f / s;
    }
    __syncthreads();

    // out0: sum O partials over 8 waves, scale, store
    if (tid < 256) {
        const int row = tid >> 4;
        const int dc  = (tid & 15) * 4;
        const float ri = Rinv[row];
        f32x4_t o = {0.f, 0.f, 0.f, 0.f};
        #pragma unroll
        for (int ww = 0; ww < 8; ++ww)
            o += *(const f32x4_t*)((const float*)(lds + ww * WVREG) + row * 64 + dc);
        o.x *= ri; o.y *= ri; o.z *= ri; o.w *= ri;
        *(f32x4_t*)(out0 + ((size_t)(b * N_ + m0 + row)) * D_ + dc) = o;
    }

    // out1: per-wave transpose bounce through small tile, coalesced f32x4 stores
    {
        char* Et = lds + EBASE + w * EW;       // [16 m][40 n] bf16, row stride 80B
        const int   rm  = l >> 2;              // store row (m)
        const int   kq  = l & 3;               // store col quarter
        const float riR = Rinv[rm];
        float* o1row = out1 + (size_t)(b * N_ + m0 + rm) * N_;
        #pragma unroll
        for (int ic = 0; ic < 8; ++ic) {
            const int nc = nc0 + ic * 32;
            bf16x4_t lo = __builtin_shufflevector(pa[ic], pa[ic], 0, 1, 2, 3);
            bf16x4_t hi = __builtin_shufflevector(pa[ic], pa[ic], 4, 5, 6, 7);
            *(bf16x4_t*)(Et + c * 80 + g * 8)      = lo;   // E[m=c][nc+4g+r]
            *(bf16x4_t*)(Et + c * 80 + 32 + g * 8) = hi;   // E[m=c][nc+16+4g+r]
            bf16x8_t er = *(const bf16x8_t*)(Et + rm * 80 + kq * 16);
            f32x4_t o0, o1;
            #pragma unroll
            for (int j = 0; j < 4; ++j) {
                o0[j] = (float)er[j]     * riR;
                o1[j] = (float)er[4 + j] * riR;
            }
            float* dst = o1row + nc + kq * 8;
            *(f32x4_t*)dst       = o0;
            *(f32x4_t*)(dst + 4) = o1;
        }
    }
}

extern "C" void kernel_launch(void* const* d_in, const int* in_sizes, int n_in,
                              void* d_out, int out_size, void* d_ws, size_t ws_size,
                              hipStream_t stream) {
    (void)in_sizes; (void)n_in; (void)out_size; (void)d_ws; (void)ws_size;
    const float* q = (const float*)d_in[0];
    const float* k = (const float*)d_in[1];
    const float* v = (const float*)d_in[2];
    const int* mask = (const int*)d_in[3];
    float* out0 = (float*)d_out;                          // [B,N,D]
    float* out1 = out0 + (size_t)B_ * N_ * D_;            // [B,N,N]
    attn_fused<<<dim3(B_ * (N_ / 16)), dim3(512), 0, stream>>>(q, k, v, mask, out0, out1);
}

// Round 5
// 265.700 us; speedup vs baseline: 1.0417x; 1.0082x over previous
//
#include <hip/hip_runtime.h>
#include <hip/hip_bf16.h>
#include <cstdint>

#define B_ 16
#define N_ 2048
#define D_ 64

typedef __bf16 bf16x8_t __attribute__((ext_vector_type(8)));
typedef __bf16 bf16x4_t __attribute__((ext_vector_type(4)));
typedef float f32x4_t __attribute__((ext_vector_type(4)));
typedef int   int4_t  __attribute__((ext_vector_type(4)));

// LDS map (bytes):
//  [0, 33792)        8 waves x VBUF(4224): V staging, single buffer, 4 subtiles x TSUB(1056).
//                    reused as per-wave O-reduction region ([16 m][64 d] f32 = 4096B) in epilogue.
//  [33792, 44032)    8 waves x 1280: E transpose tile [16 m][40 n] bf16 (row stride 80B)
//  [44032, 44544)    Lbuf: 8 waves x 16 row-sums (f32)
//  [44544, 44608)    Rinv: 16 f32
// 44608 B/block -> 3 blocks/CU (LDS-bound) = 24 waves/CU = 6 waves/SIMD.
#define TSUB  1056
#define VBUF  (4 * TSUB)           // 4224
#define EBASE (8 * VBUF)           // 33792
#define EW    1280
#define LBASE (EBASE + 8 * EW)     // 44032
#define RBASE (LBASE + 8 * 16 * 4) // 44544
#define LDSZ  (RBASE + 64)         // 44608

__device__ __forceinline__ void split8r(const f32x4_t a, const f32x4_t bq, bf16x8_t& h, bf16x8_t& lo) {
    #pragma unroll
    for (int j = 0; j < 4; ++j) {
        __bf16 h0 = (__bf16)a[j];
        h[j] = h0;     lo[j]     = (__bf16)(a[j]  - (float)h0);
        __bf16 h1 = (__bf16)bq[j];
        h[4 + j] = h1; lo[4 + j] = (__bf16)(bq[j] - (float)h1);
    }
}

__global__ __launch_bounds__(512, 2)
void attn_fused(const float* __restrict__ qg,
                const float* __restrict__ kg,
                const float* __restrict__ vg,
                const int*   __restrict__ mg,
                float* __restrict__ out0,
                float* __restrict__ out1)
{
    __shared__ __align__(16) char lds[LDSZ];

    const int tid = threadIdx.x;
    const int w = tid >> 6, l = tid & 63, g = l >> 4, c = l & 15;

    // XCD-chunked bijective swizzle (2048 blocks % 8 == 0)
    const int bid = ((int)blockIdx.x & 7) * 256 + ((int)blockIdx.x >> 3);
    const int b  = bid >> 7;
    const int m0 = (bid & 127) << 4;

    // Q as MFMA B-operand: col=c -> q-row m0+c; k-slot (g,j) <-> d = g*8+j (+32 frag1)
    bf16x8_t qh0, ql0, qh1, ql1;
    {
        const float* qrow = qg + ((size_t)(b * N_ + m0 + c)) * D_ + g * 8;
        split8r(*(const f32x4_t*)qrow, *(const f32x4_t*)(qrow + 4), qh0, ql0);
        split8r(*(const f32x4_t*)(qrow + 32), *(const f32x4_t*)(qrow + 36), qh1, ql1);
    }

    const float* kbase = kg + ((size_t)(b * N_ + c)) * D_ + g * 8;   // + nn*D_ -> K row nn+c
    const int*   mrow  = mg + (size_t)(b * N_ + m0 + c) * N_;        // mask row of q-row m0+c
    const float* vsrc0 = vg + ((size_t)(b * N_) + (l >> 3)) * D_ + (l & 7) * 8;

    char* VW = lds + w * VBUF;                 // single V buffer (per-wave, in-order LDS)
    const int tsub  = ((l & 7) >> 1) * TSUB;
    const int wrow0 = l >> 3;
    const int wcolb = (l & 1) * 16;
    const int hbit  = (l >> 5) & 1;
    const int vrd_base = g * 128 + c * 2;

    const int nc0 = w * 256;
    float lsum = 0.f;
    f32x4_t of[4] = {};     // O_unnorm: lane (g,c) holds O[m=4g+r][d=16t+c]
    bf16x8_t pa[8];         // per-chunk P rows (A-frag layout), statically indexed

    // prefetch pipeline registers: raw K (8 x f32x4) + mask (2 x int4) one chunk ahead
    f32x4_t kf[2][8];
    int4_t  mf[2][2];
    #pragma unroll
    for (int s = 0; s < 2; ++s) {
        const float* kr = kbase + (size_t)(nc0 + s * 16) * D_;
        kf[0][s * 4 + 0] = *(const f32x4_t*)(kr);
        kf[0][s * 4 + 1] = *(const f32x4_t*)(kr + 4);
        kf[0][s * 4 + 2] = *(const f32x4_t*)(kr + 32);
        kf[0][s * 4 + 3] = *(const f32x4_t*)(kr + 36);
        mf[0][s] = *(const int4_t*)(mrow + nc0 + s * 16 + g * 4);
    }

    #pragma unroll
    for (int ic = 0; ic < 8; ++ic) {
        const int nc  = nc0 + ic * 32;
        const int cur = ic & 1, nxt = cur ^ 1;

        // ---- 1. issue V loads for THIS chunk (consumed after QK^T, ~full-QK latency cover) ----
        f32x4_t vf[8];
        #pragma unroll
        for (int u = 0; u < 4; ++u) {
            const float* p = vsrc0 + (size_t)(nc + u * 8) * D_;
            vf[u * 2]     = *(const f32x4_t*)p;
            vf[u * 2 + 1] = *(const f32x4_t*)(p + 4);
        }

        // ---- 2. issue K + mask prefetch for NEXT chunk ----
        if (ic < 7) {
            #pragma unroll
            for (int s = 0; s < 2; ++s) {
                const float* kr = kbase + (size_t)(nc + 32 + s * 16) * D_;
                kf[nxt][s * 4 + 0] = *(const f32x4_t*)(kr);
                kf[nxt][s * 4 + 1] = *(const f32x4_t*)(kr + 4);
                kf[nxt][s * 4 + 2] = *(const f32x4_t*)(kr + 32);
                kf[nxt][s * 4 + 3] = *(const f32x4_t*)(kr + 36);
                mf[nxt][s] = *(const int4_t*)(mrow + nc + 32 + s * 16 + g * 4);
            }
        }

        // ---- 3. S^T = K·Q^T from prefetched regs: lane (g,c) gets S[n=nn+4g+r][m=m0+c] ----
        bf16x4_t eh[2];
        #pragma unroll
        for (int s = 0; s < 2; ++s) {
            bf16x8_t kh0, kl0, kh1, kl1;
            split8r(kf[cur][s * 4 + 0], kf[cur][s * 4 + 1], kh0, kl0);
            split8r(kf[cur][s * 4 + 2], kf[cur][s * 4 + 3], kh1, kl1);
            f32x4_t acc = {0.f, 0.f, 0.f, 0.f};
            acc = __builtin_amdgcn_mfma_f32_16x16x32_bf16(kh0, qh0, acc, 0, 0, 0);
            acc = __builtin_amdgcn_mfma_f32_16x16x32_bf16(kh1, qh1, acc, 0, 0, 0);
            acc = __builtin_amdgcn_mfma_f32_16x16x32_bf16(kl0, qh0, acc, 0, 0, 0);
            acc = __builtin_amdgcn_mfma_f32_16x16x32_bf16(kl1, qh1, acc, 0, 0, 0);
            acc = __builtin_amdgcn_mfma_f32_16x16x32_bf16(kh0, ql0, acc, 0, 0, 0);
            acc = __builtin_amdgcn_mfma_f32_16x16x32_bf16(kh1, ql1, acc, 0, 0, 0);
            const int4_t mv = mf[cur][s];
            #pragma unroll
            for (int r = 0; r < 4; ++r) {
                float ev = mv[r] ? 0.f : __expf(acc[r]);
                lsum += ev;
                eh[s][r] = (__bf16)ev;
            }
        }
        pa[ic] = __builtin_shufflevector(eh[0], eh[1], 0, 1, 2, 3, 4, 5, 6, 7);

        // ---- 4. V arrived by now: cvt + swizzled b128 stores ----
        #pragma unroll
        for (int u = 0; u < 4; ++u) {
            bf16x8_t v8;
            #pragma unroll
            for (int j = 0; j < 4; ++j) { v8[j] = (__bf16)vf[u * 2][j]; v8[4 + j] = (__bf16)vf[u * 2 + 1][j]; }
            const int off = (((wrow0 + 8 * u) * 32 + wcolb) ^ (((hbit + 2 * u) & 3) << 5));
            *(int4_t*)(VW + tsub + off) = __builtin_bit_cast(int4_t, v8);
        }

        // ---- 5. PV: A=pa (regs), B=V from swizzled LDS (conflict-free scalar reads) ----
        #pragma unroll
        for (int t = 0; t < 4; ++t) {
            const char* vs = VW + t * TSUB;
            bf16x8_t vbf;
            #pragma unroll
            for (int j = 0; j < 4; ++j) {
                const int off = vrd_base + ((j ^ g) & 3) * 32;
                vbf[j]     = *(const __bf16*)(vs + off);
                vbf[4 + j] = *(const __bf16*)(vs + off + 512);
            }
            of[t] = __builtin_amdgcn_mfma_f32_16x16x32_bf16(pa[ic], vbf, of[t], 0, 0, 0);
        }
    }

    // =============== epilogue ===============
    // O partials into own wave's (dead) V region: [16 m][64 d] f32
    {
        float* Ow = (float*)VW;
        #pragma unroll
        for (int t = 0; t < 4; ++t)
            #pragma unroll
            for (int r = 0; r < 4; ++r)
                Ow[(g * 4 + r) * 64 + t * 16 + c] = of[t][r];
    }

    // row sums: lane (g,c) has partial of row c; sum over g via shfl, stash per wave
    lsum += __shfl_xor(lsum, 16);
    lsum += __shfl_xor(lsum, 32);
    float* Lbuf = (float*)(lds + LBASE);
    if (l < 16) Lbuf[w * 16 + l] = lsum;
    __syncthreads();

    float* Rinv = (float*)(lds + RBASE);
    if (tid < 16) {
        float s = 0.f;
        #pragma unroll
        for (int ww = 0; ww < 8; ++ww) s += Lbuf[ww * 16 + tid];
        Rinv[tid] = 1.0f / s;
    }
    __syncthreads();

    // out0: sum O partials over 8 waves, scale, store
    if (tid < 256) {
        const int row = tid >> 4;
        const int dc  = (tid & 15) * 4;
        const float ri = Rinv[row];
        f32x4_t o = {0.f, 0.f, 0.f, 0.f};
        #pragma unroll
        for (int ww = 0; ww < 8; ++ww)
            o += *(const f32x4_t*)((const float*)(lds + ww * VBUF) + row * 64 + dc);
        o.x *= ri; o.y *= ri; o.z *= ri; o.w *= ri;
        *(f32x4_t*)(out0 + ((size_t)(b * N_ + m0 + row)) * D_ + dc) = o;
    }

    // out1: per-wave transpose bounce through small tile, coalesced f32x4 stores
    {
        char* Et = lds + EBASE + w * EW;       // [16 m][40 n] bf16, row stride 80B
        const int   rm  = l >> 2;              // store row (m)
        const int   kq  = l & 3;               // store col quarter
        const float riR = Rinv[rm];
        float* o1row = out1 + (size_t)(b * N_ + m0 + rm) * N_;
        #pragma unroll
        for (int ic = 0; ic < 8; ++ic) {
            const int nc = nc0 + ic * 32;
            bf16x4_t lo = __builtin_shufflevector(pa[ic], pa[ic], 0, 1, 2, 3);
            bf16x4_t hi = __builtin_shufflevector(pa[ic], pa[ic], 4, 5, 6, 7);
            *(bf16x4_t*)(Et + c * 80 + g * 8)      = lo;   // E[m=c][nc+4g+r]
            *(bf16x4_t*)(Et + c * 80 + 32 + g * 8) = hi;   // E[m=c][nc+16+4g+r]
            bf16x8_t er = *(const bf16x8_t*)(Et + rm * 80 + kq * 16);
            f32x4_t o0, o1;
            #pragma unroll
            for (int j = 0; j < 4; ++j) {
                o0[j] = (float)er[j]     * riR;
                o1[j] = (float)er[4 + j] * riR;
            }
            float* dst = o1row + nc + kq * 8;
            *(f32x4_t*)dst       = o0;
            *(f32x4_t*)(dst + 4) = o1;
        }
    }
}

extern "C" void kernel_launch(void* const* d_in, const int* in_sizes, int n_in,
                              void* d_out, int out_size, void* d_ws, size_t ws_size,
                              hipStream_t stream) {
    (void)in_sizes; (void)n_in; (void)out_size; (void)d_ws; (void)ws_size;
    const float* q = (const float*)d_in[0];
    const float* k = (const float*)d_in[1];
    const float* v = (const float*)d_in[2];
    const int* mask = (const int*)d_in[3];
    float* out0 = (float*)d_out;                          // [B,N,D]
    float* out1 = out0 + (size_t)B_ * N_ * D_;            // [B,N,N]
    attn_fused<<<dim3(B_ * (N_ / 16)), dim3(512), 0, stream>>>(q, k, v, mask, out0, out1);
}

// Round 7
// 263.960 us; speedup vs baseline: 1.0486x; 1.0066x over previous
//
#include <hip/hip_runtime.h>
#include <hip/hip_bf16.h>
#include <cstdint>

#define B_ 16
#define N_ 2048
#define D_ 64

typedef __bf16 bf16x8_t __attribute__((ext_vector_type(8)));
typedef __bf16 bf16x4_t __attribute__((ext_vector_type(4)));
typedef float f32x4_t __attribute__((ext_vector_type(4)));
typedef int   int4_t  __attribute__((ext_vector_type(4)));

// LDS map (bytes). ALL row strides are multiples of 8 so every vector LDS
// access (b64 max) is naturally aligned. No 16B LDS vector ops anywhere.
//  KHI [128 n][68 bf16]  17408      K hi tile (single-buffered)
//  KLO [128 n][68 bf16]  17408      K lo tile
//  V0  [128 n][68 bf16]  17408      V bf16, half 0
//  V1  [128 n][68 bf16]  17408      V bf16, half 1
//  M   [16 m][132 B]      2112      mask bytes
//  Et  8 w x [16][20bf16] 5120      out1 transpose bounce
//  Lb  8x16 f32            512      row-sum partials
//  Ri  16 f32               64
#define KSTR 136
#define KHI  0
#define KLO  17408
#define V0B  34816
#define V1B  52224
#define MB_  69632
#define MSTR 132
#define ETB  71744
#define LBB  76864
#define RIB  77376
#define LDSZ 77440

// RNE hi/lo split (identical numerics to the round-5 passing kernel)
__device__ __forceinline__ void split8r(const f32x4_t a, const f32x4_t bq, bf16x8_t& h, bf16x8_t& lo) {
    #pragma unroll
    for (int j = 0; j < 4; ++j) {
        __bf16 h0 = (__bf16)a[j];
        h[j] = h0;     lo[j]     = (__bf16)(a[j]  - (float)h0);
        __bf16 h1 = (__bf16)bq[j];
        h[4 + j] = h1; lo[4 + j] = (__bf16)(bq[j] - (float)h1);
    }
}
__device__ __forceinline__ void split4r(const f32x4_t a, bf16x4_t& h, bf16x4_t& lo) {
    #pragma unroll
    for (int j = 0; j < 4; ++j) {
        __bf16 h0 = (__bf16)a[j];
        h[j] = h0;  lo[j] = (__bf16)(a[j] - (float)h0);
    }
}

__device__ __forceinline__ bf16x8_t lds_read8(const char* p) {   // two aligned b64 reads
    bf16x4_t a = *(const bf16x4_t*)(p);
    bf16x4_t b = *(const bf16x4_t*)(p + 8);
    return __builtin_shufflevector(a, b, 0, 1, 2, 3, 4, 5, 6, 7);
}

__global__ __launch_bounds__(512, 4)
void attn_fused(const float* __restrict__ qg,
                const float* __restrict__ kg,
                const float* __restrict__ vg,
                const int*   __restrict__ mg,
                float* __restrict__ out0,
                float* __restrict__ out1)
{
    __shared__ __align__(16) char lds[LDSZ];

    const int tid = threadIdx.x;
    const int w = tid >> 6, l = tid & 63, g = l >> 4, c = l & 15;

    // XCD-chunked bijective swizzle (2048 % 8 == 0)
    const int bid = ((int)blockIdx.x & 7) * 256 + ((int)blockIdx.x >> 3);
    const int b  = bid >> 7;
    const int m0 = (bid & 127) << 4;

    // Q fragments (B-operand): lane(g,c) holds Q[m0+c][d=g*8+j] (+32 for *1)
    bf16x8_t qh0, ql0, qh1, ql1;
    {
        const float* qrow = qg + ((size_t)(b * N_ + m0 + c)) * D_ + g * 8;
        split8r(*(const f32x4_t*)qrow, *(const f32x4_t*)(qrow + 4), qh0, ql0);
        split8r(*(const f32x4_t*)(qrow + 32), *(const f32x4_t*)(qrow + 36), qh1, ql1);
    }

    // coalesced staging indices (thread t handles flat 16B pieces)
    const int krow_ = tid >> 4;            // + 32*u
    const int kcol_ = (tid & 15) * 4;      // floats
    const int mrow_ = tid >> 5;
    const int mcol_ = (tid & 31) * 4;      // ints
    const int* mgrow = mg + (size_t)(b * N_ + m0 + mrow_) * N_ + mcol_;

    float lsum = 0.f;
    f32x4_t of[4] = {};        // lane(g,c): O_unnorm[m=4g+r][d=16t+c]
    bf16x4_t paE[16];          // per (pair,half): P~[m0+c][u*128+16w+4g+r]

    // prologue: issue half-0 loads
    f32x4_t kin[4], vin[4]; int4_t min_;
    #pragma unroll
    for (int u = 0; u < 4; ++u) {
        const size_t roff = ((size_t)(b * N_ + krow_ + 32 * u)) * D_ + kcol_;
        kin[u] = *(const f32x4_t*)(kg + roff);
        vin[u] = *(const f32x4_t*)(vg + roff);
    }
    min_ = *(const int4_t*)(mgrow);

    #pragma unroll
    for (int p = 0; p < 8; ++p) {
        #pragma unroll
        for (int h = 0; h < 2; ++h) {
            const int nhalf = p * 256 + h * 128;
            const int vbase = h ? V1B : V0B;

            // ---- 1. stage current half: cvt + aligned b64 LDS writes ----
            #pragma unroll
            for (int u = 0; u < 4; ++u) {
                const int row = krow_ + 32 * u;
                bf16x4_t kh, klo;
                split4r(kin[u], kh, klo);
                *(bf16x4_t*)(lds + KHI + row * KSTR + kcol_ * 2) = kh;
                *(bf16x4_t*)(lds + KLO + row * KSTR + kcol_ * 2) = klo;
                bf16x4_t v4;
                #pragma unroll
                for (int j = 0; j < 4; ++j) v4[j] = (__bf16)vin[u][j];
                *(bf16x4_t*)(lds + vbase + row * KSTR + kcol_ * 2) = v4;
            }
            {
                unsigned mbytes = 0;
                #pragma unroll
                for (int j = 0; j < 4; ++j) mbytes |= (min_[j] ? 1u : 0u) << (8 * j);
                *(unsigned*)(lds + MB_ + mrow_ * MSTR + mcol_) = mbytes;
            }

            // ---- 2. issue next-half loads (in flight across the barrier + compute) ----
            if ((p < 7) || (h < 1)) {
                const int nnext = nhalf + 128;
                #pragma unroll
                for (int u = 0; u < 4; ++u) {
                    const size_t roff = ((size_t)(b * N_ + nnext + krow_ + 32 * u)) * D_ + kcol_;
                    kin[u] = *(const f32x4_t*)(kg + roff);
                    vin[u] = *(const f32x4_t*)(vg + roff);
                }
                min_ = *(const int4_t*)(mgrow + nnext);
            }
            __syncthreads();

            // ---- 3. QK^T (swapped) on this wave's 16-n band, mask, exp ----
            bf16x4_t pe;
            {
                const char* ka = lds + KHI + (16 * w + c) * KSTR + g * 16;
                const char* la = lds + KLO + (16 * w + c) * KSTR + g * 16;
                bf16x8_t ka0 = lds_read8(ka);
                bf16x8_t ka1 = lds_read8(ka + 64);
                bf16x8_t la0 = lds_read8(la);
                bf16x8_t la1 = lds_read8(la + 64);
                f32x4_t acc = {0.f, 0.f, 0.f, 0.f};
                acc = __builtin_amdgcn_mfma_f32_16x16x32_bf16(ka0, qh0, acc, 0, 0, 0);
                acc = __builtin_amdgcn_mfma_f32_16x16x32_bf16(ka1, qh1, acc, 0, 0, 0);
                acc = __builtin_amdgcn_mfma_f32_16x16x32_bf16(la0, qh0, acc, 0, 0, 0);
                acc = __builtin_amdgcn_mfma_f32_16x16x32_bf16(la1, qh1, acc, 0, 0, 0);
                acc = __builtin_amdgcn_mfma_f32_16x16x32_bf16(ka0, ql0, acc, 0, 0, 0);
                acc = __builtin_amdgcn_mfma_f32_16x16x32_bf16(ka1, ql1, acc, 0, 0, 0);
                const unsigned mu = *(const unsigned*)(lds + MB_ + c * MSTR + 16 * w + 4 * g);
                #pragma unroll
                for (int r = 0; r < 4; ++r) {
                    float e = ((mu >> (8 * r)) & 255u) ? 0.f : __expf(acc[r]);
                    lsum += e;
                    pe[r] = (__bf16)e;
                }
            }
            paE[2 * p + h] = pe;

            if (h == 0) {
                __syncthreads();          // before stage-1 overwrites K/M tiles
            } else {
                // ---- 4. PV once per pair: A=[pe_h0|pe_h1], B=V0|V1 rows 16w+4g+j ----
                bf16x8_t pa8 = __builtin_shufflevector(paE[2 * p], paE[2 * p + 1],
                                                       0, 1, 2, 3, 4, 5, 6, 7);
                #pragma unroll
                for (int t = 0; t < 4; ++t) {
                    bf16x8_t vbf;
                    #pragma unroll
                    for (int j = 0; j < 4; ++j) {
                        const int rr = 16 * w + 4 * g + j;
                        vbf[j]     = *(const __bf16*)(lds + V0B + rr * KSTR + (16 * t + c) * 2);
                        vbf[4 + j] = *(const __bf16*)(lds + V1B + rr * KSTR + (16 * t + c) * 2);
                    }
                    of[t] = __builtin_amdgcn_mfma_f32_16x16x32_bf16(pa8, vbf, of[t], 0, 0, 0);
                }
                __syncthreads();          // before next pair's stage overwrites V0/V1/K/M
            }
        }
    }

    // =============== epilogue ===============
    // O partials into (dead) K region: [w][16 m][64 d] f32
    {
        float* Ow = (float*)(lds + w * 4096);
        #pragma unroll
        for (int t = 0; t < 4; ++t)
            #pragma unroll
            for (int r = 0; r < 4; ++r)
                Ow[(g * 4 + r) * 64 + t * 16 + c] = of[t][r];
    }
    lsum += __shfl_xor(lsum, 16);
    lsum += __shfl_xor(lsum, 32);
    float* Lbuf = (float*)(lds + LBB);
    if (l < 16) Lbuf[w * 16 + l] = lsum;
    __syncthreads();

    float* Rinv = (float*)(lds + RIB);
    if (tid < 16) {
        float s = 0.f;
        #pragma unroll
        for (int ww = 0; ww < 8; ++ww) s += Lbuf[ww * 16 + tid];
        Rinv[tid] = 1.0f / s;
    }
    __syncthreads();

    // out0
    if (tid < 256) {
        const int row = tid >> 4;
        const int dc  = (tid & 15) * 4;
        const float ri = Rinv[row];
        f32x4_t o = {0.f, 0.f, 0.f, 0.f};
        #pragma unroll
        for (int ww = 0; ww < 8; ++ww)
            o += *(const f32x4_t*)((const float*)(lds + ww * 4096) + row * 64 + dc);
        o.x *= ri; o.y *= ri; o.z *= ri; o.w *= ri;
        *(f32x4_t*)(out0 + ((size_t)(b * N_ + m0 + row)) * D_ + dc) = o;
    }

    // out1: per-wave transpose bounce (Et [16][20] bf16), coalesced f32x4 stores
    {
        char* Et = lds + ETB + w * 640;
        const int   rm  = l >> 2;
        const int   kq  = l & 3;
        const float riR = Rinv[rm];
        float* o1row = out1 + (size_t)(b * N_ + m0 + rm) * N_;
        #pragma unroll
        for (int u = 0; u < 16; ++u) {
            const int n0 = u * 128 + 16 * w;
            *(bf16x4_t*)(Et + c * 40 + g * 8) = paE[u];        // E[m=c][local 4g+r]
            bf16x4_t er = *(const bf16x4_t*)(Et + rm * 40 + kq * 8);
            f32x4_t o4;
            #pragma unroll
            for (int j = 0; j < 4; ++j) o4[j] = (float)er[j] * riR;
            *(f32x4_t*)(o1row + n0 + kq * 4) = o4;
        }
    }
}

extern "C" void kernel_launch(void* const* d_in, const int* in_sizes, int n_in,
                              void* d_out, int out_size, void* d_ws, size_t ws_size,
                              hipStream_t stream) {
    (void)in_sizes; (void)n_in; (void)out_size; (void)d_ws; (void)ws_size;
    const float* q = (const float*)d_in[0];
    const float* k = (const float*)d_in[1];
    const float* v = (const float*)d_in[2];
    const int* mask = (const int*)d_in[3];
    float* out0 = (float*)d_out;                          // [B,N,D]
    float* out1 = out0 + (size_t)B_ * N_ * D_;            // [B,N,N]
    attn_fused<<<dim3(B_ * (N_ / 16)), dim3(512), 0, stream>>>(q, k, v, mask, out0, out1);
}